// Round 1
// baseline (99.224 us; speedup 1.0000x reference)
//
#include <hip/hip_runtime.h>
#include <math.h>

// Stickbreaking attention, inference (no mask): out = att @ V with
//   att[i,t] = sigmoid(s[i,t]) * exp( sum_{j>=t} -softplus(s[i,j]) ),  s = QK^T/sqrt(D)
// Weights decay ~exp(-0.8 * (S-1-t)) -> only the top ~100 columns matter.
// Streaming reverse scan over K-tiles with conservative early exit.

constexpr int B = 2, H = 16, S = 2048, D = 128;
constexpr int BQ = 64;       // query rows per block
constexpr int BK = 32;       // key cols per tile
constexpr int NT = 256;      // threads per block
constexpr int QS = 132;      // Qs LDS stride (floats), 16B-aligned pad
constexpr int KTS = 36;      // Kt LDS stride: row = one d, BK j's + pad
constexpr int SS = 36;       // Stile stride
constexpr float SCALE = 0.0883883476483184405f;  // 1/sqrt(128)
constexpr float EXIT_THR = -40.0f;  // exp(-40)=4e-18; *2048*|v| << 2.3e-2 tol

// per-step stickbreaking update, all-register (used fully unrolled)
#define SB_STEP(VAL) do {                                   \
    float x_  = (VAL);                                      \
    float en_ = __expf(-fabsf(x_));                         \
    float r_  = __fdividef(1.0f, 1.0f + en_);               \
    float z_  = (x_ >= 0.0f) ? r_ : en_ * r_;               \
    c -= (fmaxf(x_, 0.0f) + __logf(1.0f + en_));            \
    (VAL) = z_ * __expf(c);                                 \
} while (0)

__global__ __launch_bounds__(NT, 2)
void sb_attn(const float* __restrict__ q, const float* __restrict__ k,
             const float* __restrict__ v, float* __restrict__ out) {
    __shared__ float Qs[BQ][QS];   // scaled Q block
    __shared__ float Kt[D][KTS];   // transposed K tile: Kt[d][j]
    __shared__ float St[BQ][SS];   // logits, then att weights
    __shared__ int aliveFlag;

    const int tid = threadIdx.x;
    const int nqb = S / BQ;                  // 32
    const int bh = blockIdx.x / nqb;         // 0..31
    const int qb = blockIdx.x % nqb;

    const float* qbase = q + ((size_t)bh * S + (size_t)qb * BQ) * D;
    const float* kbase = k + (size_t)bh * S * D;
    const float* vbase = v + (size_t)bh * S * D;
    float* obase = out + ((size_t)bh * S + (size_t)qb * BQ) * D;

    // ---- stage Q block (scaled) ----
    #pragma unroll
    for (int it = 0; it < (BQ * D / 4) / NT; ++it) {   // 8 iters
        int flat4 = it * NT + tid;
        int i  = flat4 / (D / 4);
        int dc = flat4 % (D / 4);
        float4 val = *(const float4*)(qbase + (size_t)i * D + dc * 4);
        val.x *= SCALE; val.y *= SCALE; val.z *= SCALE; val.w *= SCALE;
        *(float4*)&Qs[i][dc * 4] = val;
    }

    // output accumulators: thread owns row pv_i = tid>>2, d = 4*pv_dq + 16*dd
    float acc[8][4];
    #pragma unroll
    for (int dd = 0; dd < 8; ++dd) {
        acc[dd][0] = 0.f; acc[dd][1] = 0.f; acc[dd][2] = 0.f; acc[dd][3] = 0.f;
    }

    const int wave = tid >> 6;
    const int lane = tid & 63;
    // QK mapping: wave handles rows wave*16..+15; lane: r=lane&15, jg=lane>>4 (8 j's)
    const int qk_i  = wave * 16 + (lane & 15);
    const int qk_jg = lane >> 4;
    // PV mapping
    const int pv_i  = tid >> 2;
    const int pv_dq = tid & 3;

    float carry = 0.0f;   // valid in wave 0 (thread 'lane' owns row 'lane')

    __syncthreads();

    const int NTILE = S / BK;  // 64
    for (int t = NTILE - 1; t >= 0; --t) {
        const int jt = t * BK;

        // ---- stage K tile transposed: Kt[d][j] = K[jt+j][d] * (scale on Q) ----
        #pragma unroll
        for (int it = 0; it < (BK * D / 4) / NT; ++it) {   // 4 iters
            int flat4 = it * NT + tid;
            int j  = flat4 / (D / 4);
            int dc = flat4 % (D / 4);
            float4 val = *(const float4*)(kbase + (size_t)(jt + j) * D + dc * 4);
            Kt[dc * 4 + 0][j] = val.x;
            Kt[dc * 4 + 1][j] = val.y;
            Kt[dc * 4 + 2][j] = val.z;
            Kt[dc * 4 + 3][j] = val.w;
        }
        __syncthreads();

        // ---- logits: each thread computes 8 j's for one row ----
        {
            float lg[8];
            #pragma unroll
            for (int jj = 0; jj < 8; ++jj) lg[jj] = 0.f;
            #pragma unroll 4
            for (int d4 = 0; d4 < D / 4; ++d4) {
                float4 qv = *(const float4*)&Qs[qk_i][d4 * 4];
                #pragma unroll
                for (int e = 0; e < 4; ++e) {
                    float qe = (e == 0) ? qv.x : (e == 1) ? qv.y : (e == 2) ? qv.z : qv.w;
                    float4 ka = *(const float4*)&Kt[d4 * 4 + e][qk_jg * 8];
                    float4 kb = *(const float4*)&Kt[d4 * 4 + e][qk_jg * 8 + 4];
                    lg[0] = fmaf(qe, ka.x, lg[0]);
                    lg[1] = fmaf(qe, ka.y, lg[1]);
                    lg[2] = fmaf(qe, ka.z, lg[2]);
                    lg[3] = fmaf(qe, ka.w, lg[3]);
                    lg[4] = fmaf(qe, kb.x, lg[4]);
                    lg[5] = fmaf(qe, kb.y, lg[5]);
                    lg[6] = fmaf(qe, kb.z, lg[6]);
                    lg[7] = fmaf(qe, kb.w, lg[7]);
                }
            }
            *(float4*)&St[qk_i][qk_jg * 8]     = make_float4(lg[0], lg[1], lg[2], lg[3]);
            *(float4*)&St[qk_i][qk_jg * 8 + 4] = make_float4(lg[4], lg[5], lg[6], lg[7]);
        }
        __syncthreads();

        // ---- reverse cumsum + weights: wave 0, one row per lane, in-register ----
        if (wave == 0) {
            float4 rv[8];
            #pragma unroll
            for (int cc = 0; cc < 8; ++cc) rv[cc] = *(const float4*)&St[lane][cc * 4];
            float c = carry;
            #pragma unroll
            for (int cc = 7; cc >= 0; --cc) {   // j descending: w,z,y,x of each float4
                SB_STEP(rv[cc].w);
                SB_STEP(rv[cc].z);
                SB_STEP(rv[cc].y);
                SB_STEP(rv[cc].x);
            }
            carry = c;
            #pragma unroll
            for (int cc = 0; cc < 8; ++cc) *(float4*)&St[lane][cc * 4] = rv[cc];
            unsigned long long alive = __ballot(carry > EXIT_THR);
            if (lane == 0) aliveFlag = (alive != 0ULL) ? 1 : 0;
        }
        __syncthreads();

        // ---- PV accumulate: V read straight from global (L1-resident tile) ----
        {
            const float* vrow = vbase + (size_t)jt * D + pv_dq * 4;
            #pragma unroll 2
            for (int j = 0; j < BK; ++j) {
                float a = St[pv_i][j];
                if (a > 1e-12f) {
                    const float* vr = vrow + (size_t)j * D;
                    #pragma unroll
                    for (int dd = 0; dd < 8; ++dd) {
                        float4 vv = *(const float4*)(vr + dd * 16);
                        acc[dd][0] = fmaf(a, vv.x, acc[dd][0]);
                        acc[dd][1] = fmaf(a, vv.y, acc[dd][1]);
                        acc[dd][2] = fmaf(a, vv.z, acc[dd][2]);
                        acc[dd][3] = fmaf(a, vv.w, acc[dd][3]);
                    }
                }
            }
        }

        int alive = aliveFlag;
        __syncthreads();
        if (!alive) break;
    }

    // ---- write output ----
    #pragma unroll
    for (int dd = 0; dd < 8; ++dd) {
        *(float4*)(obase + (size_t)pv_i * D + pv_dq * 4 + dd * 16) =
            make_float4(acc[dd][0], acc[dd][1], acc[dd][2], acc[dd][3]);
    }
}

extern "C" void kernel_launch(void* const* d_in, const int* in_sizes, int n_in,
                              void* d_out, int out_size, void* d_ws, size_t ws_size,
                              hipStream_t stream) {
    (void)in_sizes; (void)n_in; (void)out_size; (void)d_ws; (void)ws_size;
    const float* q = (const float*)d_in[0];
    const float* k = (const float*)d_in[1];
    const float* v = (const float*)d_in[2];
    float* out = (float*)d_out;
    dim3 grid(B * H * (S / BQ));   // 1024 blocks
    sb_attn<<<grid, NT, 0, stream>>>(q, k, v, out);
}

// Round 2
// 41.031 us; speedup vs baseline: 2.4183x; 2.4183x over previous
//
#include <hip/hip_runtime.h>
#include <math.h>

// Stickbreaking attention (no mask):
//   att[i,t] = sigmoid(s[i,t]) * exp( sum_{j>=t} -softplus(s[i,j]) ),  s = QK^T/sqrt(D)
// Suffix sums decay ~0.8/column => only top ~100 columns matter; reverse-stream
// K-tiles with conservative carry-based early exit (carry < -40 => rest ~ 4e-18).
//
// Structure: one wave (64 threads) per 16 query rows, fully independent:
//  - Q in registers as mfma_f32_16x16x32_f16 A-frags (split hi/lo f16 for accuracy)
//  - K/V B-frags loaded directly from global (tiles are L1/L2-resident)
//  - f32 scan across 16-lane groups via shfl suffix-scan (all lanes active)
//  - P routed through a tiny per-wave LDS buffer to transpose D-layout -> A-layout
//  - no __syncthreads anywhere; per-wave __ballot early exit

constexpr int B_ = 2, H_ = 16, S_ = 2048, D_ = 128;
constexpr int BQ = 16;       // query rows per wave-block
constexpr int BK = 32;       // key cols per tile
constexpr float SCALE = 0.08838834764831845f;   // 1/sqrt(128)
constexpr float EXIT_THR = -40.0f;

typedef _Float16 f16x8 __attribute__((ext_vector_type(8)));
typedef float f32x4 __attribute__((ext_vector_type(4)));

// sigmoid + log_sigmoid(-x) = -softplus(x), mirroring the f32 reference math
static __device__ __forceinline__ void zlb(float x, float& z, float& lb) {
    float en = __expf(-fabsf(x));
    float rc = __fdividef(1.0f, 1.0f + en);
    z  = (x >= 0.0f) ? rc : en * rc;
    lb = -(fmaxf(x, 0.0f) + __logf(1.0f + en));
}

// one Hillis-Steele suffix-scan step within 16-lane groups
static __device__ __forceinline__ float sufstep(float s, int lane, int dlt) {
    float t = __shfl(s, (lane + dlt) & 63, 64);
    return ((lane & 15) + dlt < 16) ? t : 0.0f;
}

__global__ __launch_bounds__(64, 4)
void sb_attn(const float* __restrict__ qg, const float* __restrict__ kg,
             const float* __restrict__ vg, float* __restrict__ outg) {
    __shared__ float Pw[16][34];   // P transpose buffer (stride 34 -> <=2-way banks)

    const int lane = threadIdx.x;          // 0..63
    const int g    = lane >> 4;            // 0..3
    const int m16  = lane & 15;            // 0..15

    const int nqb = S_ / BQ;               // 128
    const int bh  = blockIdx.x / nqb;
    const int qb  = blockIdx.x % nqb;

    const float* qb_p = qg + ((size_t)bh * S_ + (size_t)qb * BQ) * D_;
    const float* kb_p = kg + (size_t)bh * S_ * D_;
    const float* vb_p = vg + (size_t)bh * S_ * D_;
    float*       ob_p = outg + ((size_t)bh * S_ + (size_t)qb * BQ) * D_;

    // ---- Q A-frags (persistent): lane holds Q[m16][ck*32 + g*8 + e] * SCALE,
    //      split into f16 hi + residual lo for high-precision QK^T ----
    f16x8 qhi[4], qlo[4];
    #pragma unroll
    for (int ck = 0; ck < 4; ++ck) {
        const float* p = qb_p + (size_t)m16 * D_ + ck * 32 + g * 8;
        #pragma unroll
        for (int e = 0; e < 8; ++e) {
            float qs = p[e] * SCALE;
            _Float16 h = (_Float16)qs;
            qhi[ck][e] = h;
            qlo[ck][e] = (_Float16)(qs - (float)h);
        }
    }

    // output accumulators: D-layout, accO[ck][r] = O[4g+r][ck*16 + m16]
    f32x4 accO[8];
    #pragma unroll
    for (int ck = 0; ck < 8; ++ck) accO[ck] = (f32x4){0.f, 0.f, 0.f, 0.f};

    float Cr[4] = {0.f, 0.f, 0.f, 0.f};    // per-row carry (rows 4g+r), replicated in group

    for (int t = S_ / BK - 1; t >= 0; --t) {
        const int j0 = t * BK;

        // ---- QK^T: S[4g+r][m16 (+16)] via split-f16 MFMA (3 mfma per frag) ----
        f32x4 s0 = {0.f, 0.f, 0.f, 0.f}, s1 = {0.f, 0.f, 0.f, 0.f};
        #pragma unroll
        for (int ck = 0; ck < 4; ++ck) {
            const float* kp0 = kb_p + (size_t)(j0 + m16) * D_ + ck * 32 + g * 8;
            const float* kp1 = kp0 + (size_t)16 * D_;
            f16x8 khi0, klo0, khi1, klo1;
            #pragma unroll
            for (int e = 0; e < 8; ++e) {
                float kv0 = kp0[e];
                _Float16 h0 = (_Float16)kv0;
                khi0[e] = h0; klo0[e] = (_Float16)(kv0 - (float)h0);
                float kv1 = kp1[e];
                _Float16 h1 = (_Float16)kv1;
                khi1[e] = h1; klo1[e] = (_Float16)(kv1 - (float)h1);
            }
            s0 = __builtin_amdgcn_mfma_f32_16x16x32_f16(qhi[ck], khi0, s0, 0, 0, 0);
            s0 = __builtin_amdgcn_mfma_f32_16x16x32_f16(qlo[ck], khi0, s0, 0, 0, 0);
            s0 = __builtin_amdgcn_mfma_f32_16x16x32_f16(qhi[ck], klo0, s0, 0, 0, 0);
            s1 = __builtin_amdgcn_mfma_f32_16x16x32_f16(qhi[ck], khi1, s1, 0, 0, 0);
            s1 = __builtin_amdgcn_mfma_f32_16x16x32_f16(qlo[ck], khi1, s1, 0, 0, 0);
            s1 = __builtin_amdgcn_mfma_f32_16x16x32_f16(qhi[ck], klo1, s1, 0, 0, 0);
        }

        // ---- stickbreaking scan (f32): per row 4g+r, j descending 31..0.
        //      lane holds j = m16 (s0) and j = 16+m16 (s1). Suffix sums are
        //      INCLUSIVE of own column (matches reference tril). ----
        float w0a[4], w1a[4];
        #pragma unroll
        for (int r = 0; r < 4; ++r) {
            float z0, lb0, z1, lb1;
            zlb(s0[r], z0, lb0);
            zlb(s1[r], z1, lb1);
            float ss1 = lb1, ss0 = lb0;
            #pragma unroll
            for (int dlt = 1; dlt < 16; dlt <<= 1) {
                ss1 += sufstep(ss1, lane, dlt);
                ss0 += sufstep(ss0, lane, dlt);
            }
            float tot = __shfl(ss0 + ss1, lane & 48, 64);  // group-lane0: tile total
            float T1  = __shfl(ss1,       lane & 48, 64);  // total of upper half
            float c   = Cr[r];
            w1a[r] = z1 * __expf(c + ss1);          // j in [16,32)
            w0a[r] = z0 * __expf(c + T1 + ss0);     // j in [0,16)
            Cr[r]  = c + tot;
        }

        // ---- transpose P: D-layout -> A-frag layout via per-wave LDS ----
        #pragma unroll
        for (int r = 0; r < 4; ++r) {
            Pw[g * 4 + r][m16]      = w0a[r];
            Pw[g * 4 + r][16 + m16] = w1a[r];
        }
        f16x8 pf;
        {
            const float* pr = &Pw[m16][g * 8];
            #pragma unroll
            for (int e = 0; e < 8; ++e) pf[e] = (_Float16)pr[e];
        }

        // ---- PV: O += P @ V, V B-frags direct from global ----
        #pragma unroll
        for (int ck = 0; ck < 8; ++ck) {
            f16x8 vf;
            #pragma unroll
            for (int e = 0; e < 8; ++e)
                vf[e] = (_Float16)vb_p[(size_t)(j0 + g * 8 + e) * D_ + ck * 16 + m16];
            accO[ck] = __builtin_amdgcn_mfma_f32_16x16x32_f16(pf, vf, accO[ck], 0, 0, 0);
        }

        // ---- early exit: all 16 rows dead => remaining weights <= e^-40 ----
        float cm = fmaxf(fmaxf(Cr[0], Cr[1]), fmaxf(Cr[2], Cr[3]));
        if (__ballot(cm > EXIT_THR) == 0ULL) break;
    }

    // ---- write output: O[4g+r][ck*16 + m16] ----
    #pragma unroll
    for (int ck = 0; ck < 8; ++ck) {
        #pragma unroll
        for (int r = 0; r < 4; ++r) {
            ob_p[(size_t)(g * 4 + r) * D_ + ck * 16 + m16] = accO[ck][r];
        }
    }
}

extern "C" void kernel_launch(void* const* d_in, const int* in_sizes, int n_in,
                              void* d_out, int out_size, void* d_ws, size_t ws_size,
                              hipStream_t stream) {
    (void)in_sizes; (void)n_in; (void)out_size; (void)d_ws; (void)ws_size;
    const float* q = (const float*)d_in[0];
    const float* k = (const float*)d_in[1];
    const float* v = (const float*)d_in[2];
    float* out = (float*)d_out;
    dim3 grid(B_ * H_ * (S_ / BQ));   // 4096 wave-blocks
    sb_attn<<<grid, 64, 0, stream>>>(q, k, v, out);
}

// Round 4
// 40.504 us; speedup vs baseline: 2.4497x; 1.0130x over previous
//
#include <hip/hip_runtime.h>
#include <math.h>

// Stickbreaking attention (no mask):
//   att[i,t] = sigmoid(s[i,t]) * exp( sum_{j>=t} -softplus(s[i,j]) ),  s = QK^T/sqrt(D)
// Carry decays ~0.8/column => only top ~100 columns matter. Reverse-stream
// K-tiles, per-wave early exit when all 16 rows' carry < -40.
//
// v3b: pre-kernel converts the top 256 columns of K (bf16 hi/lo split) and V
// (f16, transposed) into d_ws once; main kernel = 1 wave / 16 rows, transposed
// QK^T (mfma(K,Q)) so the scan is lane-local: 6 shfls/tile instead of 40,
// zero dtype-conversion VALU on the hot path, all-16B loads.
// (v3 fix: cvt_pkrtz returns __fp16 vector, not _Float16 vector.)

constexpr int B_ = 2, H_ = 16, S_ = 2048, D_ = 128;
constexpr int BK = 32, NTILES = S_ / BK;    // 64 tiles
constexpr int NJ = 256, NFT = NJ / BK;      // 8 precomputed "fast" tiles
constexpr float SCALE = 0.08838834764831845f;   // 1/sqrt(128)
constexpr float EXIT_THR = -40.0f;

typedef __attribute__((ext_vector_type(8))) short bf16x8;
typedef __attribute__((ext_vector_type(8))) _Float16 f16x8;
typedef __attribute__((ext_vector_type(8))) unsigned short u16x8;
typedef __attribute__((ext_vector_type(4))) float f32x4;
typedef __attribute__((ext_vector_type(2))) __fp16 fp16v2;

static __device__ __forceinline__ unsigned short bf16rtn(float x) {
    unsigned int u = __float_as_uint(x);
    u += 0x7FFFu + ((u >> 16) & 1u);
    return (unsigned short)(u >> 16);
}

// sigmoid(x) and log_sigmoid(-x) = -softplus(x), f32 (mirrors reference)
static __device__ __forceinline__ void zlb(float x, float& z, float& lb) {
    float en = __expf(-fabsf(x));
    float rc = __fdividef(1.0f, 1.0f + en);
    z  = (x >= 0.0f) ? rc : en * rc;
    lb = -(fmaxf(x, 0.0f) + __logf(1.0f + en));
}

// ---------------- pre-kernel: convert top-256 columns of K and V ----------------
// blocks [0,512): K -> khi/klo bf16, row-major [bh][jj][d]
// blocks [512,768): V -> vt f16, transposed per 32-tile: [bh][tt][d][j32]
__global__ __launch_bounds__(256)
void sb_pre(const float* __restrict__ kg, const float* __restrict__ vg,
            unsigned short* __restrict__ khi, unsigned short* __restrict__ klo,
            unsigned short* __restrict__ vt) {
    __shared__ float Vs[32][132];
    const int tid = threadIdx.x;
    const int blk = blockIdx.x;
    if (blk < 512) {
        size_t flat = ((size_t)blk * 256 + tid) * 8;
        int bh = (int)(flat / (NJ * D_));
        int rem = (int)(flat % (NJ * D_));
        int jj = rem / D_, d0 = rem % D_;
        const float* src = kg + ((size_t)bh * S_ + (S_ - NJ) + jj) * D_ + d0;
        u16x8 h8, l8;
        #pragma unroll
        for (int e = 0; e < 8; ++e) {
            float x = src[e];
            unsigned short hb = bf16rtn(x);
            float hf = __uint_as_float((unsigned int)hb << 16);
            h8[e] = hb;
            l8[e] = bf16rtn(x - hf);
        }
        size_t o = ((size_t)bh * NJ + jj) * D_ + d0;
        *(u16x8*)(khi + o) = h8;
        *(u16x8*)(klo + o) = l8;
    } else {
        int vb = blk - 512;
        int bh = vb >> 3, tt = vb & 7;
        const float* src = vg + ((size_t)bh * S_ + (S_ - NJ) + tt * 32) * D_;
        #pragma unroll
        for (int it = 0; it < 4; ++it) {
            int idx = it * 256 + tid;
            int j = idx >> 5, d4 = idx & 31;
            float4 val = *(const float4*)(src + (size_t)j * D_ + d4 * 4);
            *(float4*)&Vs[j][d4 * 4] = val;
        }
        __syncthreads();
        int d = tid >> 1, jh = (tid & 1) << 4;
        f16x8 v0, v1;
        #pragma unroll
        for (int j2 = 0; j2 < 8; ++j2) v0[j2] = (_Float16)Vs[jh + j2][d];
        #pragma unroll
        for (int j2 = 0; j2 < 8; ++j2) v1[j2] = (_Float16)Vs[jh + 8 + j2][d];
        unsigned short* dst = vt + (((size_t)bh * NFT + tt) * D_ + d) * 32 + jh;
        *(f16x8*)dst = v0;
        *(f16x8*)(dst + 8) = v1;
    }
}

// ---------------- per-tile step ----------------
template<bool FAST>
static __device__ __forceinline__ float tile_step(
    int t, int lane, int g, int m16, int bh,
    const float* kb_p, const float* vb_p,
    const unsigned short* __restrict__ khi, const unsigned short* __restrict__ klo,
    const unsigned short* __restrict__ vt,
    const bf16x8* qhi, const bf16x8* qlo,
    f32x4* accO, unsigned int (*Pw)[20], float carry)
{
    const int j0 = t * BK;
    const int tt = t - (NTILES - NFT);
    f32x4 st0 = {0.f, 0.f, 0.f, 0.f}, st1 = {0.f, 0.f, 0.f, 0.f};

    if constexpr (FAST) {
        const size_t rb = ((size_t)bh * NJ + (size_t)(tt * 32 + m16)) * D_;
        const unsigned short* kr0h = khi + rb;
        const unsigned short* kr1h = kr0h + 16 * D_;
        const unsigned short* kr0l = klo + rb;
        const unsigned short* kr1l = kr0l + 16 * D_;
        #pragma unroll
        for (int ck = 0; ck < 4; ++ck) {
            const int off = ck * 32 + g * 8;
            bf16x8 kh0 = *(const bf16x8*)(kr0h + off);
            bf16x8 kl0 = *(const bf16x8*)(kr0l + off);
            bf16x8 kh1 = *(const bf16x8*)(kr1h + off);
            bf16x8 kl1 = *(const bf16x8*)(kr1l + off);
            st0 = __builtin_amdgcn_mfma_f32_16x16x32_bf16(kh0, qhi[ck], st0, 0, 0, 0);
            st0 = __builtin_amdgcn_mfma_f32_16x16x32_bf16(kl0, qhi[ck], st0, 0, 0, 0);
            st0 = __builtin_amdgcn_mfma_f32_16x16x32_bf16(kh0, qlo[ck], st0, 0, 0, 0);
            st1 = __builtin_amdgcn_mfma_f32_16x16x32_bf16(kh1, qhi[ck], st1, 0, 0, 0);
            st1 = __builtin_amdgcn_mfma_f32_16x16x32_bf16(kl1, qhi[ck], st1, 0, 0, 0);
            st1 = __builtin_amdgcn_mfma_f32_16x16x32_bf16(kh1, qlo[ck], st1, 0, 0, 0);
        }
    } else {
        const float* kr0 = kb_p + (size_t)(j0 + m16) * D_;
        const float* kr1 = kr0 + (size_t)16 * D_;
        #pragma unroll
        for (int ck = 0; ck < 4; ++ck) {
            bf16x8 kh0, kl0, kh1, kl1;
            #pragma unroll
            for (int e = 0; e < 8; ++e) {
                float x0 = kr0[ck * 32 + g * 8 + e];
                unsigned short h0 = bf16rtn(x0);
                kh0[e] = (short)h0;
                kl0[e] = (short)bf16rtn(x0 - __uint_as_float((unsigned int)h0 << 16));
                float x1 = kr1[ck * 32 + g * 8 + e];
                unsigned short h1 = bf16rtn(x1);
                kh1[e] = (short)h1;
                kl1[e] = (short)bf16rtn(x1 - __uint_as_float((unsigned int)h1 << 16));
            }
            st0 = __builtin_amdgcn_mfma_f32_16x16x32_bf16(kh0, qhi[ck], st0, 0, 0, 0);
            st0 = __builtin_amdgcn_mfma_f32_16x16x32_bf16(kl0, qhi[ck], st0, 0, 0, 0);
            st0 = __builtin_amdgcn_mfma_f32_16x16x32_bf16(kh0, qlo[ck], st0, 0, 0, 0);
            st1 = __builtin_amdgcn_mfma_f32_16x16x32_bf16(kh1, qhi[ck], st1, 0, 0, 0);
            st1 = __builtin_amdgcn_mfma_f32_16x16x32_bf16(kl1, qhi[ck], st1, 0, 0, 0);
            st1 = __builtin_amdgcn_mfma_f32_16x16x32_bf16(kh1, qlo[ck], st1, 0, 0, 0);
        }
    }

    // ---- lane-local stickbreaking scan: row i=m16, j = j0 + {4g+r, 16+4g+r} ----
    float lbL[4], lbU[4], zL[4], zU[4];
    #pragma unroll
    for (int r = 0; r < 4; ++r) { zlb(st0[r], zL[r], lbL[r]); zlb(st1[r], zU[r], lbU[r]); }
    float sL3 = lbL[3], sL2 = lbL[2] + sL3, sL1 = lbL[1] + sL2, sL0 = lbL[0] + sL1;
    float sU3 = lbU[3], sU2 = lbU[2] + sU3, sU1 = lbU[1] + sU2, sU0 = lbU[0] + sU1;
    float sufL[4] = {sL0, sL1, sL2, sL3};
    float sufU[4] = {sU0, sU1, sU2, sU3};
    float TL = sL0, TU = sU0;
    float IU = TU, IL = TL;
    { float t1 = __shfl(IU, (lane + 16) & 63); if (g < 3) IU += t1;
      float t2 = __shfl(IU, (lane + 32) & 63); if (g < 2) IU += t2; }
    { float t1 = __shfl(IL, (lane + 16) & 63); if (g < 3) IL += t1;
      float t2 = __shfl(IL, (lane + 32) & 63); if (g < 2) IL += t2; }
    float TotU = __shfl(IU, m16);   // g=0 lane holds full upper-half sum
    float EU = IU - TU, EL = IL - TL;
    float bU = carry + EU;
    float bL = carry + TotU + EL;
    float wU[4], wL[4];
    #pragma unroll
    for (int r = 0; r < 4; ++r) {
        wU[r] = zU[r] * __expf(bU + sufU[r]);
        wL[r] = zL[r] * __expf(bL + sufL[r]);
    }
    float TotL = __shfl(IL, m16);
    carry += TotU + TotL;

    // ---- pack P to f16, transpose D-layout -> A-layout via per-wave LDS ----
    union { fp16v2 h; unsigned int u; } cA, cB, cC, cD;
    cA.h = __builtin_amdgcn_cvt_pkrtz(wL[0], wL[1]);
    cB.h = __builtin_amdgcn_cvt_pkrtz(wL[2], wL[3]);
    cC.h = __builtin_amdgcn_cvt_pkrtz(wU[0], wU[1]);
    cD.h = __builtin_amdgcn_cvt_pkrtz(wU[2], wU[3]);
    *(uint2*)&Pw[m16][2 * g]     = make_uint2(cA.u, cB.u);
    *(uint2*)&Pw[m16][8 + 2 * g] = make_uint2(cC.u, cD.u);
    f16x8 pf = *(const f16x8*)&Pw[m16][4 * g];   // P[i=m16][j0 + g*8 + e]

    // ---- PV: O += P @ V ----
    #pragma unroll
    for (int ck = 0; ck < 8; ++ck) {
        f16x8 vf;
        if constexpr (FAST) {
            const unsigned short* vp =
                vt + (((size_t)bh * NFT + tt) * D_ + ck * 16 + m16) * 32 + g * 8;
            vf = *(const f16x8*)vp;
        } else {
            #pragma unroll
            for (int e = 0; e < 8; ++e)
                vf[e] = (_Float16)vb_p[(size_t)(j0 + g * 8 + e) * D_ + ck * 16 + m16];
        }
        accO[ck] = __builtin_amdgcn_mfma_f32_16x16x32_f16(pf, vf, accO[ck], 0, 0, 0);
    }
    return carry;
}

// ---------------- main kernel: 1 wave per 16 query rows ----------------
template<int NFAST>
__global__ __launch_bounds__(64, 4)
void sb_attn(const float* __restrict__ qg, const float* __restrict__ kg,
             const float* __restrict__ vg, float* __restrict__ outg,
             const unsigned short* __restrict__ khi,
             const unsigned short* __restrict__ klo,
             const unsigned short* __restrict__ vt) {
    __shared__ unsigned int Pw[16][20];

    const int lane = threadIdx.x;
    const int g = lane >> 4, m16 = lane & 15;

    // XCD-chunked swizzle: 4096 = 8 XCDs * 512; same-head waves share an XCD L2
    const int bid = blockIdx.x;
    const int wg  = ((bid & 7) << 9) | (bid >> 3);
    const int bh  = wg >> 7;           // / 128
    const int qb  = wg & 127;

    const float* qb_p = qg + ((size_t)bh * S_ + (size_t)qb * 16) * D_;
    const float* kb_p = kg + (size_t)bh * S_ * D_;
    const float* vb_p = vg + (size_t)bh * S_ * D_;
    float*       ob_p = outg + ((size_t)bh * S_ + (size_t)qb * 16) * D_;

    // Q frags (persistent, bf16 hi/lo): lane holds Q[m16][ck*32+g*8+e]*SCALE
    bf16x8 qhi[4], qlo[4];
    #pragma unroll
    for (int ck = 0; ck < 4; ++ck) {
        const float* p = qb_p + (size_t)m16 * D_ + ck * 32 + g * 8;
        #pragma unroll
        for (int e = 0; e < 8; ++e) {
            float x = p[e] * SCALE;
            unsigned short hb = bf16rtn(x);
            float hf = __uint_as_float((unsigned int)hb << 16);
            qhi[ck][e] = (short)hb;
            qlo[ck][e] = (short)bf16rtn(x - hf);
        }
    }

    f32x4 accO[8];
    #pragma unroll
    for (int ck = 0; ck < 8; ++ck) accO[ck] = (f32x4){0.f, 0.f, 0.f, 0.f};

    float carry = 0.f;
    bool alive = true;
    int t = NTILES - 1;

    if constexpr (NFAST > 0) {
        for (; t >= NTILES - NFAST; --t) {
            carry = tile_step<true>(t, lane, g, m16, bh, kb_p, vb_p, khi, klo, vt,
                                    qhi, qlo, accO, Pw, carry);
            if (__ballot(carry > EXIT_THR) == 0ULL) { alive = false; break; }
        }
    }
    if (alive) {
        for (; t >= 0; --t) {
            carry = tile_step<false>(t, lane, g, m16, bh, kb_p, vb_p, khi, klo, vt,
                                     qhi, qlo, accO, Pw, carry);
            if (__ballot(carry > EXIT_THR) == 0ULL) break;
        }
    }

    // write O[4g+r][ck*16+m16]
    #pragma unroll
    for (int ck = 0; ck < 8; ++ck) {
        #pragma unroll
        for (int r = 0; r < 4; ++r) {
            ob_p[(size_t)(g * 4 + r) * D_ + ck * 16 + m16] = accO[ck][r];
        }
    }
}

extern "C" void kernel_launch(void* const* d_in, const int* in_sizes, int n_in,
                              void* d_out, int out_size, void* d_ws, size_t ws_size,
                              hipStream_t stream) {
    (void)in_sizes; (void)n_in; (void)out_size;
    const float* q = (const float*)d_in[0];
    const float* k = (const float*)d_in[1];
    const float* v = (const float*)d_in[2];
    float* out = (float*)d_out;

    const size_t kbytes = (size_t)B_ * H_ * NJ * D_ * 2;   // 2 MiB each
    const size_t need = 3 * kbytes;                        // khi + klo + vt
    unsigned short* khi = (unsigned short*)d_ws;
    unsigned short* klo = khi + (size_t)B_ * H_ * NJ * D_;
    unsigned short* vt  = klo + (size_t)B_ * H_ * NJ * D_;

    dim3 grid(B_ * H_ * (S_ / 16));   // 4096 wave-blocks

    if (ws_size >= need) {
        sb_pre<<<768, 256, 0, stream>>>(k, v, khi, klo, vt);
        sb_attn<NFT><<<grid, 64, 0, stream>>>(q, k, v, out, khi, klo, vt);
    } else {
        sb_attn<0><<<grid, 64, 0, stream>>>(q, k, v, out, khi, klo, vt);
    }
}